// Round 1
// baseline (107.493 us; speedup 1.0000x reference)
//
#include <hip/hip_runtime.h>

constexpr int BLOCK = 256;
constexpr int PPT   = 4;   // points per thread

__global__ __launch_bounds__(BLOCK) void essential_msac_kernel(
    const float*  __restrict__ models,  // B x 3 x 4
    const float4* __restrict__ pts,     // N x (x1,y1,x2,y2)
    const float*  __restrict__ K1,      // 3x3
    const float*  __restrict__ K2,      // 3x3
    float*        __restrict__ out,     // B x N
    int B, int N)
{
    const int b = blockIdx.y;

    // Threshold (uniform across grid)
    const float f1 = (K1[0] + K1[4]) * 0.5f;
    const float f2 = (K2[0] + K2[4]) * 0.5f;
    const float thr = (1.0f / f1 + 1.0f / f2) * 0.5f;
    const float inv_thr2 = 1.0f / (thr * thr);

    // E = skew(t) @ R, uniform per block (L1-broadcast loads, cheap)
    // models[b] layout row-major (3,4): R[k][j] = m[k*4+j], t[k] = m[k*4+3]
    const float* m = models + (size_t)b * 12;
    const float t0 = m[3], t1 = m[7], t2 = m[11];
    float E[9];
    #pragma unroll
    for (int j = 0; j < 3; ++j) {
        const float R0 = m[0 + j], R1 = m[4 + j], R2 = m[8 + j];
        E[0 + j] = fmaf(-t2, R1,  t1 * R2);   // row 0:  -t2*R1 + t1*R2
        E[3 + j] = fmaf( t2, R0, -t0 * R2);   // row 1:   t2*R0 - t0*R2
        E[6 + j] = fmaf(-t1, R0,  t0 * R1);   // row 2:  -t1*R0 + t0*R1
    }

    const int n0 = (blockIdx.x * BLOCK + threadIdx.x) * PPT;
    if (n0 >= N) return;

    float r[PPT];
    #pragma unroll
    for (int k = 0; k < PPT; ++k) {
        const int n = n0 + k;
        if (n >= N) { r[k] = 0.0f; continue; }
        const float4 p = pts[n];
        const float x = p.x, y = p.y;     // hom1 = (x, y, 1)
        const float u = p.z, v = p.w;     // hom2 = (u, v, 1)

        // M_x1 = E @ hom1  (rows 0,1 only needed)
        const float a0 = fmaf(E[0], x, fmaf(E[1], y, E[2]));
        const float a1 = fmaf(E[3], x, fmaf(E[4], y, E[5]));
        // M_x2 = E^T @ hom2
        const float b0 = fmaf(E[0], u, fmaf(E[3], v, E[6]));
        const float b1 = fmaf(E[1], u, fmaf(E[4], v, E[7]));
        const float b2 = fmaf(E[2], u, fmaf(E[5], v, E[8]));

        const float jj = fmaf(a0, a0, fmaf(a1, a1, fmaf(b0, b0, b1 * b1)));
        const float s  = fmaf(x, b0, fmaf(y, b1, b2));
        const float d  = __fdividef(s * s, jj) * inv_thr2;
        r[k] = 1.0f - fminf(fmaxf(d, 0.0f), 1.0f);
    }

    float* o = out + (size_t)b * N + n0;
    if (n0 + PPT <= N) {
        // N = 100000 is divisible by 4, so this path is 16B-aligned
        *reinterpret_cast<float4*>(o) = make_float4(r[0], r[1], r[2], r[3]);
    } else {
        for (int k = 0; k < PPT && n0 + k < N; ++k) o[k] = r[k];
    }
}

extern "C" void kernel_launch(void* const* d_in, const int* in_sizes, int n_in,
                              void* d_out, int out_size, void* d_ws, size_t ws_size,
                              hipStream_t stream)
{
    const float* models = (const float*)d_in[0];
    const float* points = (const float*)d_in[1];
    const float* K1     = (const float*)d_in[2];
    const float* K2     = (const float*)d_in[3];
    float* out = (float*)d_out;

    const int B = in_sizes[0] / 12;   // (B,3,4)
    const int N = in_sizes[1] / 4;    // (N,4)

    dim3 grid((N + BLOCK * PPT - 1) / (BLOCK * PPT), B);
    essential_msac_kernel<<<grid, BLOCK, 0, stream>>>(
        models, (const float4*)points, K1, K2, out, B, N);
}

// Round 3
// 53.941 us; speedup vs baseline: 1.9928x; 1.9928x over previous
//
#include <hip/hip_runtime.h>

typedef float floatx4 __attribute__((ext_vector_type(4)));  // native vec for nontemporal store

constexpr int BLOCK = 256;
constexpr int PPT   = 4;    // points per thread
constexpr int MPB   = 16;   // models per block

__global__ __launch_bounds__(BLOCK) void essential_msac_kernel(
    const float*  __restrict__ models,  // B x 3 x 4
    const float4* __restrict__ pts,     // N x (x1,y1,x2,y2)
    const float*  __restrict__ K1,      // 3x3
    const float*  __restrict__ K2,      // 3x3
    float*        __restrict__ out,     // B x N
    int B, int N)
{
    __shared__ float Es[MPB][9];

    const int bm0  = blockIdx.y * MPB;
    const int mEnd = min(MPB, B - bm0);

    // First mEnd threads each build one E = skew(t) @ R into LDS.
    if ((int)threadIdx.x < mEnd) {
        const float* m = models + (size_t)(bm0 + threadIdx.x) * 12;
        const float t0 = m[3], t1 = m[7], t2 = m[11];
        #pragma unroll
        for (int j = 0; j < 3; ++j) {
            const float R0 = m[0 + j], R1 = m[4 + j], R2 = m[8 + j];
            Es[threadIdx.x][0 + j] = fmaf(-t2, R1,  t1 * R2);
            Es[threadIdx.x][3 + j] = fmaf( t2, R0, -t0 * R2);
            Es[threadIdx.x][6 + j] = fmaf(-t1, R0,  t0 * R1);
        }
    }
    __syncthreads();

    const float f1 = (K1[0] + K1[4]) * 0.5f;
    const float f2 = (K2[0] + K2[4]) * 0.5f;
    const float thr = (1.0f / f1 + 1.0f / f2) * 0.5f;
    const float inv_thr2 = 1.0f / (thr * thr);

    const int n0 = (blockIdx.x * BLOCK + threadIdx.x) * PPT;
    if (n0 >= N) return;
    const bool full = (n0 + PPT <= N);   // N % 4 == 0 -> aligned float4 path

    // Load this thread's 4 points ONCE; reuse across all MPB models.
    float4 p[PPT];
    #pragma unroll
    for (int k = 0; k < PPT; ++k)
        p[k] = (full || n0 + k < N) ? pts[n0 + k] : make_float4(0.f, 0.f, 0.f, 1.f);

    float* o = out + (size_t)bm0 * N + n0;
    for (int mi = 0; mi < mEnd; ++mi) {
        float E[9];
        #pragma unroll
        for (int j = 0; j < 9; ++j) E[j] = Es[mi][j];   // LDS broadcast

        float r[PPT];
        #pragma unroll
        for (int k = 0; k < PPT; ++k) {
            const float x = p[k].x, y = p[k].y;   // hom1 = (x, y, 1)
            const float u = p[k].z, v = p[k].w;   // hom2 = (u, v, 1)

            // M_x1 = E @ hom1 (rows 0,1), M_x2 = E^T @ hom2
            const float a0 = fmaf(E[0], x, fmaf(E[1], y, E[2]));
            const float a1 = fmaf(E[3], x, fmaf(E[4], y, E[5]));
            const float b0 = fmaf(E[0], u, fmaf(E[3], v, E[6]));
            const float b1 = fmaf(E[1], u, fmaf(E[4], v, E[7]));
            const float b2 = fmaf(E[2], u, fmaf(E[5], v, E[8]));

            const float jj = fmaf(a0, a0, fmaf(a1, a1, fmaf(b0, b0, b1 * b1)));
            const float s  = fmaf(x, b0, fmaf(y, b1, b2));
            const float d  = __fdividef(s * s, jj) * inv_thr2;
            r[k] = 1.0f - fminf(fmaxf(d, 0.0f), 1.0f);
        }

        if (full) {
            floatx4 v4 = { r[0], r[1], r[2], r[3] };
            __builtin_nontemporal_store(v4, reinterpret_cast<floatx4*>(o));
        } else {
            for (int k = 0; k < PPT && n0 + k < N; ++k)
                __builtin_nontemporal_store(r[k], o + k);
        }
        o += N;   // next model's row
    }
}

extern "C" void kernel_launch(void* const* d_in, const int* in_sizes, int n_in,
                              void* d_out, int out_size, void* d_ws, size_t ws_size,
                              hipStream_t stream)
{
    const float* models = (const float*)d_in[0];
    const float* points = (const float*)d_in[1];
    const float* K1     = (const float*)d_in[2];
    const float* K2     = (const float*)d_in[3];
    float* out = (float*)d_out;

    const int B = in_sizes[0] / 12;   // (B,3,4)
    const int N = in_sizes[1] / 4;    // (N,4)

    dim3 grid((N + BLOCK * PPT - 1) / (BLOCK * PPT), (B + MPB - 1) / MPB);
    essential_msac_kernel<<<grid, BLOCK, 0, stream>>>(
        models, (const float4*)points, K1, K2, out, B, N);
}